// Round 1
// baseline (959.166 us; speedup 1.0000x reference)
//
#include <hip/hip_runtime.h>

// Product VQ: B=64, T=2048, D=512, C=4, K=128, d=128.
// Round 3: latency-bound fix.
//   - 512-thread blocks (8 waves share the 35 KB LDS stage) -> 32 waves/CU (was 16)
//   - per-nt fused MFMA+top2 scan: 1 live f32x4 acc instead of 8 (VGPR <= 64 target)
//   - parallel epilogue: quad-group g owns rows 4g..4g+3 (winners already resident
//     in its lanes post-merge -> no broadcast shfls); gathers issued as independent
//     16-lane x float4 batches (256 B coalesced), 2 rows in flight
//   - rare fp64 exact re-eval now a 16-lane cooperative reduce in the owning quad

#define NTOK 131072
#define DF   512
#define CS   4
#define DS   128
#define KC   128
#define PITCH 136   // f16 units per LDS code row (128 + 8 pad)
#define TAU  0.5f

typedef _Float16 half8 __attribute__((ext_vector_type(8)));
typedef float   f32x4 __attribute__((ext_vector_type(4)));

__device__ __forceinline__ double sq8(float4 x0, float4 x1, float4 a0, float4 a1) {
  double s = (double)(x0.x - a0.x) * (x0.x - a0.x);
  s += (double)(x0.y - a0.y) * (x0.y - a0.y);
  s += (double)(x0.z - a0.z) * (x0.z - a0.z);
  s += (double)(x0.w - a0.w) * (x0.w - a0.w);
  s += (double)(x1.x - a1.x) * (x1.x - a1.x);
  s += (double)(x1.y - a1.y) * (x1.y - a1.y);
  s += (double)(x1.z - a1.z) * (x1.z - a1.z);
  s += (double)(x1.w - a1.w) * (x1.w - a1.w);
  return s;
}

__global__ __launch_bounds__(512, 8)
void pvq_main(const float* __restrict__ inp, const float* __restrict__ emb,
              float* __restrict__ outq, int* __restrict__ idx_ws,
              float* __restrict__ dist_ws) {
  __shared__ _Float16 elds[KC * PITCH];  // 34 KB
  __shared__ float    e2s[KC];

  const int c    = blockIdx.y;
  const int t    = threadIdx.x;
  const int lane = t & 63;
  const int wid  = t >> 6;
  const int nf   = lane & 15;   // code index within 16-tile / A row index
  const int quad = lane >> 4;

  const float* ebase = emb + (size_t)c * KC * DS;

  // ---- stage e -> f16 LDS (coalesced float4) ----
  {
    const float4* eg = (const float4*)ebase;
    #pragma unroll
    for (int it = 0; it < 8; ++it) {
      int i = it * 512 + t;            // 0..4095
      float4 v = eg[i];
      int code = i >> 5;               // 32 float4 per code row
      int dpos = (i & 31) << 2;
      _Float16* p = &elds[code * PITCH + dpos];
      p[0] = (_Float16)v.x; p[1] = (_Float16)v.y;
      p[2] = (_Float16)v.z; p[3] = (_Float16)v.w;
    }
    // exact fp32 0.5*|e_k|^2, one thread per code (reads global, L2-hot)
    if (t < KC) {
      const float4* er = (const float4*)(ebase + (size_t)t * DS);
      float s = 0.f;
      #pragma unroll 8
      for (int i = 0; i < 32; ++i) {
        float4 v = er[i];
        s = fmaf(v.x, v.x, s); s = fmaf(v.y, v.y, s);
        s = fmaf(v.z, v.z, s); s = fmaf(v.w, v.w, s);
      }
      e2s[t] = 0.5f * s;
    }
  }
  __syncthreads();

  // ---- 2 row-tiles (16 rows each) per wave; block covers 256 rows ----
  const int rowblk = blockIdx.x * 256 + wid * 32;
  #pragma unroll 1
  for (int tile = 0; tile < 2; ++tile) {
    const int n0 = rowblk + tile * 16;
    const float* xrow = inp + (size_t)(n0 + nf) * DF + c * DS;

    // A-frags (row = nf, depth chunk = quad*8 + j + 32*kc) + |x_row|^2 partial
    half8 afrag[4];
    float x2 = 0.f;
    #pragma unroll
    for (int kc4 = 0; kc4 < 4; ++kc4) {
      const float4* xp = (const float4*)(xrow + kc4 * 32 + quad * 8);
      float4 v0 = xp[0], v1 = xp[1];
      x2 = fmaf(v0.x, v0.x, x2); x2 = fmaf(v0.y, v0.y, x2);
      x2 = fmaf(v0.z, v0.z, x2); x2 = fmaf(v0.w, v0.w, x2);
      x2 = fmaf(v1.x, v1.x, x2); x2 = fmaf(v1.y, v1.y, x2);
      x2 = fmaf(v1.z, v1.z, x2); x2 = fmaf(v1.w, v1.w, x2);
      afrag[kc4][0] = (_Float16)v0.x; afrag[kc4][1] = (_Float16)v0.y;
      afrag[kc4][2] = (_Float16)v0.z; afrag[kc4][3] = (_Float16)v0.w;
      afrag[kc4][4] = (_Float16)v1.x; afrag[kc4][5] = (_Float16)v1.y;
      afrag[kc4][6] = (_Float16)v1.z; afrag[kc4][7] = (_Float16)v1.w;
    }
    // full |x_row|^2 to every lane holding that row (reduce across quads)
    x2 += __shfl_xor(x2, 16);
    x2 += __shfl_xor(x2, 32);

    // ---- fused MFMA + per-lane top-2: only one f32x4 acc live at a time ----
    float s1[4], s2[4]; int k1[4], k2[4];
    #pragma unroll
    for (int r = 0; r < 4; ++r) { s1[r] = 1e30f; s2[r] = 1e30f; k1[r] = 0; k2[r] = 0; }
    #pragma unroll
    for (int nt = 0; nt < 8; ++nt) {
      f32x4 acc = (f32x4){0.f, 0.f, 0.f, 0.f};
      #pragma unroll
      for (int kc4 = 0; kc4 < 4; ++kc4) {
        half8 b = *(const half8*)&elds[(nt * 16 + nf) * PITCH + kc4 * 32 + quad * 8];
        acc = __builtin_amdgcn_mfma_f32_16x16x32_f16(afrag[kc4], b, acc, 0, 0, 0);
      }
      const float e2v = e2s[nt * 16 + nf];
      const int kidx = nt * 16 + nf;
      #pragma unroll
      for (int r = 0; r < 4; ++r) {
        float s = e2v - acc[r];
        if (s < s1[r])      { s2[r] = s1[r]; k2[r] = k1[r]; s1[r] = s; k1[r] = kidx; }
        else if (s < s2[r]) { s2[r] = s;     k2[r] = kidx; }
      }
    }

    // ---- merge across the 16 lanes of each quad-group ----
    #pragma unroll
    for (int off = 1; off < 16; off <<= 1) {
      #pragma unroll
      for (int r = 0; r < 4; ++r) {
        float o1 = __shfl_xor(s1[r], off); int ok1 = __shfl_xor(k1[r], off);
        float o2 = __shfl_xor(s2[r], off); int ok2 = __shfl_xor(k2[r], off);
        bool takeo = (o1 < s1[r]) || (o1 == s1[r] && ok1 < k1[r]);
        float w1 = takeo ? o1 : s1[r]; int wk1 = takeo ? ok1 : k1[r];
        float l1 = takeo ? s1[r] : o1; int lk1 = takeo ? k1[r] : ok1;
        float n2 = l1; int nk2 = lk1;
        if (s2[r] < n2) { n2 = s2[r]; nk2 = k2[r]; }
        if (o2 < n2)    { n2 = o2;    nk2 = ok2;  }
        s1[r] = w1; k1[r] = wk1; s2[r] = n2; k2[r] = nk2;
      }
    }

    // ---- winners: quad-group g owns rows n0 + 4g + r (values quad-uniform) ----
    int kbv[4]; float pv[4];
    #pragma unroll
    for (int r = 0; r < 4; ++r) {
      const int row = quad * 4 + r;
      const float x2r = __shfl(x2, row);   // lane 'row' has nf==row -> full |x|^2
      if (s2[r] - s1[r] < TAU) {
        // exact fp64 re-eval of both candidates, 16-lane cooperative (quad-uniform branch)
        int kb = k1[r], kb2 = k2[r];
        const float4* xp = (const float4*)(inp + (size_t)(n0 + row) * DF + c * DS);
        const float4* eA = (const float4*)(ebase + (size_t)kb  * DS);
        const float4* eB = (const float4*)(ebase + (size_t)kb2 * DS);
        float4 x0 = xp[2 * nf], x1v = xp[2 * nf + 1];
        float4 a0 = eA[2 * nf], a1 = eA[2 * nf + 1];
        float4 b0 = eB[2 * nf], b1 = eB[2 * nf + 1];
        double pA = sq8(x0, x1v, a0, a1);
        double pB = sq8(x0, x1v, b0, b1);
        #pragma unroll
        for (int off = 1; off < 16; off <<= 1) {   // partners within own quad: active
          pA += __shfl_xor(pA, off);
          pB += __shfl_xor(pB, off);
        }
        if (pB < pA || (pB == pA && kb2 < kb)) { kbv[r] = kb2; pv[r] = (float)pB; }
        else                                   { kbv[r] = kb;  pv[r] = (float)pA; }
      } else {
        kbv[r] = k1[r];
        pv[r]  = x2r + 2.f * s1[r];
      }
    }

    // ---- gather exact fp32 code rows + store, 2 rows in flight per batch ----
    #pragma unroll
    for (int rb = 0; rb < 4; rb += 2) {
      const float4* e0 = (const float4*)(ebase + (size_t)kbv[rb]     * DS);
      const float4* e1 = (const float4*)(ebase + (size_t)kbv[rb + 1] * DS);
      float4 q0a = e0[2 * nf], q0b = e0[2 * nf + 1];
      float4 q1a = e1[2 * nf], q1b = e1[2 * nf + 1];
      float4* o0 = (float4*)(outq + (size_t)(n0 + quad * 4 + rb)     * DF + c * DS);
      float4* o1 = (float4*)(outq + (size_t)(n0 + quad * 4 + rb + 1) * DF + c * DS);
      o0[2 * nf] = q0a; o0[2 * nf + 1] = q0b;
      o1[2 * nf] = q1a; o1[2 * nf + 1] = q1b;
    }
    if (nf == 0) {
      #pragma unroll
      for (int r = 0; r < 4; ++r) {
        const int n = n0 + quad * 4 + r;
        idx_ws[n * CS + c]  = kbv[r];
        dist_ws[n * CS + c] = pv[r];
      }
    }
  }
}

__global__ void pvq_tail(const int* __restrict__ idx_ws,
                         const float* __restrict__ dist_ws,
                         float* __restrict__ out_enc,
                         float* __restrict__ out_loss) {
  int n = blockIdx.x * blockDim.x + threadIdx.x;
  if (n >= NTOK) return;
  int4   k  = *(const int4*)&idx_ws[(size_t)n * 4];
  float4 dv = *(const float4*)&dist_ws[(size_t)n * 4];
  int enc = ((k.x * KC + k.y) * KC + k.z) * KC + k.w;
  out_enc[n]  = (float)enc;
  out_loss[n] = 1.25f * (((dv.x + dv.y) + dv.z) + dv.w);
}

extern "C" void kernel_launch(void* const* d_in, const int* in_sizes, int n_in,
                              void* d_out, int out_size, void* d_ws, size_t ws_size,
                              hipStream_t stream) {
  const float* inp = (const float*)d_in[0];
  const float* emb = (const float*)d_in[1];

  float* outq     = (float*)d_out;
  float* out_enc  = outq + (size_t)NTOK * DF;
  float* out_loss = out_enc + NTOK;

  int*   idx_ws  = (int*)d_ws;
  float* dist_ws = (float*)d_ws + (size_t)NTOK * CS;

  dim3 grid(NTOK / 256, CS);   // 512 x 4
  pvq_main<<<grid, 512, 0, stream>>>(inp, emb, outq, idx_ws, dist_ws);
  pvq_tail<<<(NTOK + 255) / 256, 256, 0, stream>>>(idx_ws, dist_ws, out_enc, out_loss);
}

// Round 3
// 935.996 us; speedup vs baseline: 1.0248x; 1.0248x over previous
//
#include <hip/hip_runtime.h>

// Product VQ: B=64, T=2048, D=512, C=4, K=128, d=128.
// Round 4 (resubmit — previous bench died on container infra, no kernel signal).
//   - 512-thread blocks, 32 waves/CU occupancy retained from R3
//   - outq stores CONTIGUOUS per instruction: lane nf writes o[nf] and
//     o[16+nf] (per quad: 256 B runs = full 128 B lines; no RFO/partial-line RMW).
//     R3's o[2nf]/o[2nf+1] pattern half-dirtied every line -> +268 MB fetch,
//     +567 MB write (measured).
//   - e2 fused into the staging loop (32-lane shfl tree per code group);
//     removes the second 64 KB/block global embedding read pass.

#define NTOK 131072
#define DF   512
#define CS   4
#define DS   128
#define KC   128
#define PITCH 136   // f16 units per LDS code row (128 + 8 pad)
#define TAU  0.5f

typedef _Float16 half8 __attribute__((ext_vector_type(8)));
typedef float   f32x4 __attribute__((ext_vector_type(4)));

__device__ __forceinline__ double sq8(float4 x0, float4 x1, float4 a0, float4 a1) {
  double s = (double)(x0.x - a0.x) * (x0.x - a0.x);
  s += (double)(x0.y - a0.y) * (x0.y - a0.y);
  s += (double)(x0.z - a0.z) * (x0.z - a0.z);
  s += (double)(x0.w - a0.w) * (x0.w - a0.w);
  s += (double)(x1.x - a1.x) * (x1.x - a1.x);
  s += (double)(x1.y - a1.y) * (x1.y - a1.y);
  s += (double)(x1.z - a1.z) * (x1.z - a1.z);
  s += (double)(x1.w - a1.w) * (x1.w - a1.w);
  return s;
}

__global__ __launch_bounds__(512, 8)
void pvq_main(const float* __restrict__ inp, const float* __restrict__ emb,
              float* __restrict__ outq, int* __restrict__ idx_ws,
              float* __restrict__ dist_ws) {
  __shared__ _Float16 elds[KC * PITCH];  // 34 KB
  __shared__ float    e2s[KC];

  const int c    = blockIdx.y;
  const int t    = threadIdx.x;
  const int lane = t & 63;
  const int wid  = t >> 6;
  const int nf   = lane & 15;   // code index within 16-tile / A row index
  const int quad = lane >> 4;

  const float* ebase = emb + (size_t)c * KC * DS;

  // ---- stage e -> f16 LDS (coalesced float4), e2 fused via 32-lane tree ----
  // iteration 'it': thread t handles chunk i = it*512+t; code = i>>5, so each
  // code's 32 chunks live in 32 CONSECUTIVE threads (= one aligned 32-lane half).
  {
    const float4* eg = (const float4*)ebase;
    #pragma unroll
    for (int it = 0; it < 8; ++it) {
      int i = it * 512 + t;            // 0..4095
      float4 v = eg[i];
      int code = i >> 5;               // 32 float4 per code row
      int dpos = (i & 31) << 2;
      _Float16* p = &elds[code * PITCH + dpos];
      p[0] = (_Float16)v.x; p[1] = (_Float16)v.y;
      p[2] = (_Float16)v.z; p[3] = (_Float16)v.w;
      // fp32 partial |e|^2 for this 4-float chunk, reduce across the code group
      float s = fmaf(v.x, v.x, fmaf(v.y, v.y, fmaf(v.z, v.z, v.w * v.w)));
      #pragma unroll
      for (int off = 1; off < 32; off <<= 1) s += __shfl_xor(s, off);
      if ((t & 31) == 0) e2s[code] = 0.5f * s;
    }
  }
  __syncthreads();

  // ---- 2 row-tiles (16 rows each) per wave; block covers 256 rows ----
  const int rowblk = blockIdx.x * 256 + wid * 32;
  #pragma unroll 1
  for (int tile = 0; tile < 2; ++tile) {
    const int n0 = rowblk + tile * 16;
    const float* xrow = inp + (size_t)(n0 + nf) * DF + c * DS;

    // A-frags (row = nf, depth chunk = quad*8 + j + 32*kc) + |x_row|^2 partial
    half8 afrag[4];
    float x2 = 0.f;
    #pragma unroll
    for (int kc4 = 0; kc4 < 4; ++kc4) {
      const float4* xp = (const float4*)(xrow + kc4 * 32 + quad * 8);
      float4 v0 = xp[0], v1 = xp[1];
      x2 = fmaf(v0.x, v0.x, x2); x2 = fmaf(v0.y, v0.y, x2);
      x2 = fmaf(v0.z, v0.z, x2); x2 = fmaf(v0.w, v0.w, x2);
      x2 = fmaf(v1.x, v1.x, x2); x2 = fmaf(v1.y, v1.y, x2);
      x2 = fmaf(v1.z, v1.z, x2); x2 = fmaf(v1.w, v1.w, x2);
      afrag[kc4][0] = (_Float16)v0.x; afrag[kc4][1] = (_Float16)v0.y;
      afrag[kc4][2] = (_Float16)v0.z; afrag[kc4][3] = (_Float16)v0.w;
      afrag[kc4][4] = (_Float16)v1.x; afrag[kc4][5] = (_Float16)v1.y;
      afrag[kc4][6] = (_Float16)v1.z; afrag[kc4][7] = (_Float16)v1.w;
    }
    // full |x_row|^2 to every lane holding that row (reduce across quads)
    x2 += __shfl_xor(x2, 16);
    x2 += __shfl_xor(x2, 32);

    // ---- fused MFMA + per-lane top-2: only one f32x4 acc live at a time ----
    float s1[4], s2[4]; int k1[4], k2[4];
    #pragma unroll
    for (int r = 0; r < 4; ++r) { s1[r] = 1e30f; s2[r] = 1e30f; k1[r] = 0; k2[r] = 0; }
    #pragma unroll
    for (int nt = 0; nt < 8; ++nt) {
      f32x4 acc = (f32x4){0.f, 0.f, 0.f, 0.f};
      #pragma unroll
      for (int kc4 = 0; kc4 < 4; ++kc4) {
        half8 b = *(const half8*)&elds[(nt * 16 + nf) * PITCH + kc4 * 32 + quad * 8];
        acc = __builtin_amdgcn_mfma_f32_16x16x32_f16(afrag[kc4], b, acc, 0, 0, 0);
      }
      const float e2v = e2s[nt * 16 + nf];
      const int kidx = nt * 16 + nf;
      #pragma unroll
      for (int r = 0; r < 4; ++r) {
        float s = e2v - acc[r];
        if (s < s1[r])      { s2[r] = s1[r]; k2[r] = k1[r]; s1[r] = s; k1[r] = kidx; }
        else if (s < s2[r]) { s2[r] = s;     k2[r] = kidx; }
      }
    }

    // ---- merge across the 16 lanes of each quad-group ----
    #pragma unroll
    for (int off = 1; off < 16; off <<= 1) {
      #pragma unroll
      for (int r = 0; r < 4; ++r) {
        float o1 = __shfl_xor(s1[r], off); int ok1 = __shfl_xor(k1[r], off);
        float o2 = __shfl_xor(s2[r], off); int ok2 = __shfl_xor(k2[r], off);
        bool takeo = (o1 < s1[r]) || (o1 == s1[r] && ok1 < k1[r]);
        float w1 = takeo ? o1 : s1[r]; int wk1 = takeo ? ok1 : k1[r];
        float l1 = takeo ? s1[r] : o1; int lk1 = takeo ? k1[r] : ok1;
        float n2 = l1; int nk2 = lk1;
        if (s2[r] < n2) { n2 = s2[r]; nk2 = k2[r]; }
        if (o2 < n2)    { n2 = o2;    nk2 = ok2;  }
        s1[r] = w1; k1[r] = wk1; s2[r] = n2; k2[r] = nk2;
      }
    }

    // ---- winners: quad-group g owns rows n0 + 4g + r (values quad-uniform) ----
    int kbv[4]; float pv[4];
    #pragma unroll
    for (int r = 0; r < 4; ++r) {
      const int row = quad * 4 + r;
      const float x2r = __shfl(x2, row);   // lane 'row' has nf==row -> full |x|^2
      if (s2[r] - s1[r] < TAU) {
        // exact fp64 re-eval of both candidates, 16-lane cooperative (quad-uniform branch)
        int kb = k1[r], kb2 = k2[r];
        const float4* xp = (const float4*)(inp + (size_t)(n0 + row) * DF + c * DS);
        const float4* eA = (const float4*)(ebase + (size_t)kb  * DS);
        const float4* eB = (const float4*)(ebase + (size_t)kb2 * DS);
        float4 x0 = xp[nf], x1v = xp[16 + nf];
        float4 a0 = eA[nf], a1 = eA[16 + nf];
        float4 b0 = eB[nf], b1 = eB[16 + nf];
        double pA = sq8(x0, x1v, a0, a1);
        double pB = sq8(x0, x1v, b0, b1);
        #pragma unroll
        for (int off = 1; off < 16; off <<= 1) {   // partners within own quad: active
          pA += __shfl_xor(pA, off);
          pB += __shfl_xor(pB, off);
        }
        if (pB < pA || (pB == pA && kb2 < kb)) { kbv[r] = kb2; pv[r] = (float)pB; }
        else                                   { kbv[r] = kb;  pv[r] = (float)pA; }
      } else {
        kbv[r] = k1[r];
        pv[r]  = x2r + 2.f * s1[r];
      }
    }

    // ---- gather fp32 code rows + store; CONTIGUOUS per instruction:
    // lane nf covers bytes [16*nf, 16*nf+16) then [256+16*nf, ...) of the
    // 512 B row segment -> per quad each store = 256 B run = full lines.
    #pragma unroll
    for (int rb = 0; rb < 4; rb += 2) {
      const float4* e0 = (const float4*)(ebase + (size_t)kbv[rb]     * DS);
      const float4* e1 = (const float4*)(ebase + (size_t)kbv[rb + 1] * DS);
      float4 q0a = e0[nf], q0b = e0[16 + nf];
      float4 q1a = e1[nf], q1b = e1[16 + nf];
      float4* o0 = (float4*)(outq + (size_t)(n0 + quad * 4 + rb)     * DF + c * DS);
      float4* o1 = (float4*)(outq + (size_t)(n0 + quad * 4 + rb + 1) * DF + c * DS);
      o0[nf] = q0a; o0[16 + nf] = q0b;
      o1[nf] = q1a; o1[16 + nf] = q1b;
    }
    if (nf == 0) {
      #pragma unroll
      for (int r = 0; r < 4; ++r) {
        const int n = n0 + quad * 4 + r;
        idx_ws[n * CS + c]  = kbv[r];
        dist_ws[n * CS + c] = pv[r];
      }
    }
  }
}

__global__ void pvq_tail(const int* __restrict__ idx_ws,
                         const float* __restrict__ dist_ws,
                         float* __restrict__ out_enc,
                         float* __restrict__ out_loss) {
  int n = blockIdx.x * blockDim.x + threadIdx.x;
  if (n >= NTOK) return;
  int4   k  = *(const int4*)&idx_ws[(size_t)n * 4];
  float4 dv = *(const float4*)&dist_ws[(size_t)n * 4];
  int enc = ((k.x * KC + k.y) * KC + k.z) * KC + k.w;
  out_enc[n]  = (float)enc;
  out_loss[n] = 1.25f * (((dv.x + dv.y) + dv.z) + dv.w);
}

extern "C" void kernel_launch(void* const* d_in, const int* in_sizes, int n_in,
                              void* d_out, int out_size, void* d_ws, size_t ws_size,
                              hipStream_t stream) {
  const float* inp = (const float*)d_in[0];
  const float* emb = (const float*)d_in[1];

  float* outq     = (float*)d_out;
  float* out_enc  = outq + (size_t)NTOK * DF;
  float* out_loss = out_enc + NTOK;

  int*   idx_ws  = (int*)d_ws;
  float* dist_ws = (float*)d_ws + (size_t)NTOK * CS;

  dim3 grid(NTOK / 256, CS);   // 512 x 4
  pvq_main<<<grid, 512, 0, stream>>>(inp, emb, outq, idx_ws, dist_ws);
  pvq_tail<<<(NTOK + 255) / 256, 256, 0, stream>>>(idx_ws, dist_ws, out_enc, out_loss);
}

// Round 4
// 925.985 us; speedup vs baseline: 1.0358x; 1.0108x over previous
//
#include <hip/hip_runtime.h>

// Product VQ: B=64, T=2048, D=512, C=4, K=128, d=128.
// Round 5: kill the scratch spill that R3 introduced.
//   - R3/R4's __launch_bounds__(512,8) capped VGPR at 64; allocator spilled
//     (reported VGPR=32, impossible for ~60 live regs). Scratch traffic matched
//     the +249 MB fetch / +567 MB write excess exactly. Store-pattern theory
//     was falsified (R4 counters identical to R3).
//   - Now (512,6): 85-VGPR budget, 3 blocks/CU (LDS 106KB), 24 waves/CU = 75%.
//   - Workspace planar [c][n] (was [n][c]): each wave owns exactly one 128 B
//     line per array -> no cross-block partial-line RMW on idx/dist.
//   - Keeps: fused e2 staging, quad-parallel epilogue, contiguous outq stores.

#define NTOK 131072
#define DF   512
#define CS   4
#define DS   128
#define KC   128
#define PITCH 136   // f16 units per LDS code row (128 + 8 pad)
#define TAU  0.5f

typedef _Float16 half8 __attribute__((ext_vector_type(8)));
typedef float   f32x4 __attribute__((ext_vector_type(4)));

__device__ __forceinline__ double sq8(float4 x0, float4 x1, float4 a0, float4 a1) {
  double s = (double)(x0.x - a0.x) * (x0.x - a0.x);
  s += (double)(x0.y - a0.y) * (x0.y - a0.y);
  s += (double)(x0.z - a0.z) * (x0.z - a0.z);
  s += (double)(x0.w - a0.w) * (x0.w - a0.w);
  s += (double)(x1.x - a1.x) * (x1.x - a1.x);
  s += (double)(x1.y - a1.y) * (x1.y - a1.y);
  s += (double)(x1.z - a1.z) * (x1.z - a1.z);
  s += (double)(x1.w - a1.w) * (x1.w - a1.w);
  return s;
}

__global__ __launch_bounds__(512, 6)
void pvq_main(const float* __restrict__ inp, const float* __restrict__ emb,
              float* __restrict__ outq, int* __restrict__ idx_ws,
              float* __restrict__ dist_ws) {
  __shared__ _Float16 elds[KC * PITCH];  // 34 KB
  __shared__ float    e2s[KC];

  const int c    = blockIdx.y;
  const int t    = threadIdx.x;
  const int lane = t & 63;
  const int wid  = t >> 6;
  const int nf   = lane & 15;   // code index within 16-tile / A row index
  const int quad = lane >> 4;

  const float* ebase = emb + (size_t)c * KC * DS;

  // ---- stage e -> f16 LDS (coalesced float4), e2 fused via 32-lane tree ----
  {
    const float4* eg = (const float4*)ebase;
    #pragma unroll
    for (int it = 0; it < 8; ++it) {
      int i = it * 512 + t;            // 0..4095
      float4 v = eg[i];
      int code = i >> 5;               // 32 float4 per code row
      int dpos = (i & 31) << 2;
      _Float16* p = &elds[code * PITCH + dpos];
      p[0] = (_Float16)v.x; p[1] = (_Float16)v.y;
      p[2] = (_Float16)v.z; p[3] = (_Float16)v.w;
      // fp32 partial |e|^2 for this 4-float chunk, reduce across the code group
      float s = fmaf(v.x, v.x, fmaf(v.y, v.y, fmaf(v.z, v.z, v.w * v.w)));
      #pragma unroll
      for (int off = 1; off < 32; off <<= 1) s += __shfl_xor(s, off);
      if ((t & 31) == 0) e2s[code] = 0.5f * s;
    }
  }
  __syncthreads();

  // ---- 2 row-tiles (16 rows each) per wave; block covers 256 rows ----
  const int rowblk = blockIdx.x * 256 + wid * 32;
  #pragma unroll 1
  for (int tile = 0; tile < 2; ++tile) {
    const int n0 = rowblk + tile * 16;
    const float* xrow = inp + (size_t)(n0 + nf) * DF + c * DS;

    // A-frags (row = nf, depth chunk = quad*8 + j + 32*kc) + |x_row|^2 partial
    half8 afrag[4];
    float x2 = 0.f;
    #pragma unroll
    for (int kc4 = 0; kc4 < 4; ++kc4) {
      const float4* xp = (const float4*)(xrow + kc4 * 32 + quad * 8);
      float4 v0 = xp[0], v1 = xp[1];
      x2 = fmaf(v0.x, v0.x, x2); x2 = fmaf(v0.y, v0.y, x2);
      x2 = fmaf(v0.z, v0.z, x2); x2 = fmaf(v0.w, v0.w, x2);
      x2 = fmaf(v1.x, v1.x, x2); x2 = fmaf(v1.y, v1.y, x2);
      x2 = fmaf(v1.z, v1.z, x2); x2 = fmaf(v1.w, v1.w, x2);
      afrag[kc4][0] = (_Float16)v0.x; afrag[kc4][1] = (_Float16)v0.y;
      afrag[kc4][2] = (_Float16)v0.z; afrag[kc4][3] = (_Float16)v0.w;
      afrag[kc4][4] = (_Float16)v1.x; afrag[kc4][5] = (_Float16)v1.y;
      afrag[kc4][6] = (_Float16)v1.z; afrag[kc4][7] = (_Float16)v1.w;
    }
    // full |x_row|^2 to every lane holding that row (reduce across quads)
    x2 += __shfl_xor(x2, 16);
    x2 += __shfl_xor(x2, 32);

    // ---- fused MFMA + per-lane top-2: only one f32x4 acc live at a time ----
    float s1[4], s2[4]; int k1[4], k2[4];
    #pragma unroll
    for (int r = 0; r < 4; ++r) { s1[r] = 1e30f; s2[r] = 1e30f; k1[r] = 0; k2[r] = 0; }
    #pragma unroll
    for (int nt = 0; nt < 8; ++nt) {
      f32x4 acc = (f32x4){0.f, 0.f, 0.f, 0.f};
      #pragma unroll
      for (int kc4 = 0; kc4 < 4; ++kc4) {
        half8 b = *(const half8*)&elds[(nt * 16 + nf) * PITCH + kc4 * 32 + quad * 8];
        acc = __builtin_amdgcn_mfma_f32_16x16x32_f16(afrag[kc4], b, acc, 0, 0, 0);
      }
      const float e2v = e2s[nt * 16 + nf];
      const int kidx = nt * 16 + nf;
      #pragma unroll
      for (int r = 0; r < 4; ++r) {
        float s = e2v - acc[r];
        if (s < s1[r])      { s2[r] = s1[r]; k2[r] = k1[r]; s1[r] = s; k1[r] = kidx; }
        else if (s < s2[r]) { s2[r] = s;     k2[r] = kidx; }
      }
    }

    // ---- merge across the 16 lanes of each quad-group ----
    #pragma unroll
    for (int off = 1; off < 16; off <<= 1) {
      #pragma unroll
      for (int r = 0; r < 4; ++r) {
        float o1 = __shfl_xor(s1[r], off); int ok1 = __shfl_xor(k1[r], off);
        float o2 = __shfl_xor(s2[r], off); int ok2 = __shfl_xor(k2[r], off);
        bool takeo = (o1 < s1[r]) || (o1 == s1[r] && ok1 < k1[r]);
        float w1 = takeo ? o1 : s1[r]; int wk1 = takeo ? ok1 : k1[r];
        float l1 = takeo ? s1[r] : o1; int lk1 = takeo ? k1[r] : ok1;
        float n2 = l1; int nk2 = lk1;
        if (s2[r] < n2) { n2 = s2[r]; nk2 = k2[r]; }
        if (o2 < n2)    { n2 = o2;    nk2 = ok2;  }
        s1[r] = w1; k1[r] = wk1; s2[r] = n2; k2[r] = nk2;
      }
    }

    // ---- winners: quad-group g owns rows n0 + 4g + r (values quad-uniform) ----
    int kbv[4]; float pv[4];
    #pragma unroll
    for (int r = 0; r < 4; ++r) {
      const int row = quad * 4 + r;
      const float x2r = __shfl(x2, row);   // lane 'row' has nf==row -> full |x|^2
      if (s2[r] - s1[r] < TAU) {
        // exact fp64 re-eval of both candidates, 16-lane cooperative (quad-uniform branch)
        int kb = k1[r], kb2 = k2[r];
        const float4* xp = (const float4*)(inp + (size_t)(n0 + row) * DF + c * DS);
        const float4* eA = (const float4*)(ebase + (size_t)kb  * DS);
        const float4* eB = (const float4*)(ebase + (size_t)kb2 * DS);
        float4 x0 = xp[nf], x1v = xp[16 + nf];
        float4 a0 = eA[nf], a1 = eA[16 + nf];
        float4 b0 = eB[nf], b1 = eB[16 + nf];
        double pA = sq8(x0, x1v, a0, a1);
        double pB = sq8(x0, x1v, b0, b1);
        #pragma unroll
        for (int off = 1; off < 16; off <<= 1) {   // partners within own quad: active
          pA += __shfl_xor(pA, off);
          pB += __shfl_xor(pB, off);
        }
        if (pB < pA || (pB == pA && kb2 < kb)) { kbv[r] = kb2; pv[r] = (float)pB; }
        else                                   { kbv[r] = kb;  pv[r] = (float)pA; }
      } else {
        kbv[r] = k1[r];
        pv[r]  = x2r + 2.f * s1[r];
      }
    }

    // ---- gather fp32 code rows + store; contiguous 256 B per quad per instr ----
    #pragma unroll
    for (int rb = 0; rb < 4; rb += 2) {
      const float4* e0 = (const float4*)(ebase + (size_t)kbv[rb]     * DS);
      const float4* e1 = (const float4*)(ebase + (size_t)kbv[rb + 1] * DS);
      float4 q0a = e0[nf], q0b = e0[16 + nf];
      float4 q1a = e1[nf], q1b = e1[16 + nf];
      float4* o0 = (float4*)(outq + (size_t)(n0 + quad * 4 + rb)     * DF + c * DS);
      float4* o1 = (float4*)(outq + (size_t)(n0 + quad * 4 + rb + 1) * DF + c * DS);
      o0[nf] = q0a; o0[16 + nf] = q0b;
      o1[nf] = q1a; o1[16 + nf] = q1b;
    }
    // planar [c][n] workspace: wave's 32 tokens = one 128 B line per array
    if (nf == 0) {
      #pragma unroll
      for (int r = 0; r < 4; ++r) {
        const int n = n0 + quad * 4 + r;
        idx_ws[(size_t)c * NTOK + n]  = kbv[r];
        dist_ws[(size_t)c * NTOK + n] = pv[r];
      }
    }
  }
}

__global__ void pvq_tail(const int* __restrict__ idx_ws,
                         const float* __restrict__ dist_ws,
                         float* __restrict__ out_enc,
                         float* __restrict__ out_loss) {
  int n = blockIdx.x * blockDim.x + threadIdx.x;
  if (n >= NTOK) return;
  int   kx = idx_ws[n];
  int   ky = idx_ws[NTOK + n];
  int   kz = idx_ws[2 * NTOK + n];
  int   kw = idx_ws[3 * NTOK + n];
  float dx = dist_ws[n];
  float dy = dist_ws[NTOK + n];
  float dz = dist_ws[2 * NTOK + n];
  float dw = dist_ws[3 * NTOK + n];
  int enc = ((kx * KC + ky) * KC + kz) * KC + kw;
  out_enc[n]  = (float)enc;
  out_loss[n] = 1.25f * (((dx + dy) + dz) + dw);
}

extern "C" void kernel_launch(void* const* d_in, const int* in_sizes, int n_in,
                              void* d_out, int out_size, void* d_ws, size_t ws_size,
                              hipStream_t stream) {
  const float* inp = (const float*)d_in[0];
  const float* emb = (const float*)d_in[1];

  float* outq     = (float*)d_out;
  float* out_enc  = outq + (size_t)NTOK * DF;
  float* out_loss = out_enc + NTOK;

  int*   idx_ws  = (int*)d_ws;
  float* dist_ws = (float*)d_ws + (size_t)NTOK * CS;

  dim3 grid(NTOK / 256, CS);   // 512 x 4
  pvq_main<<<grid, 512, 0, stream>>>(inp, emb, outq, idx_ws, dist_ws);
  pvq_tail<<<(NTOK + 255) / 256, 256, 0, stream>>>(idx_ws, dist_ws, out_enc, out_loss);
}

// Round 5
// 774.858 us; speedup vs baseline: 1.2379x; 1.1950x over previous
//
#include <hip/hip_runtime.h>

// Product VQ: B=64, T=2048, D=512, C=4, K=128, d=128.
// Round 6: scalarize all hot-path arrays (rule #20 — runtime-index-suspect C
// arrays go to scratch wholesale; counters showed ~21 KB/wave/tile of scratch
// r/w matching s1/s2/k1/k2 being memory-resident through the nt-loop).
//   - s1/s2/k1/k2 -> 16 named scalars (TOP2/MERGE macros)
//   - afrag[4] -> af0..af3, kbv/pv -> kb0..kb3/p0..p3
//   - merge 'off' loop serialized (#pragma unroll 1) to cap shuffle-temp pressure
//   - keeps: 512-thread blocks, lb(512,6), fused e2 staging, planar workspace,
//     quad-parallel epilogue, contiguous outq stores.

#define NTOK 131072
#define DF   512
#define CS   4
#define DS   128
#define KC   128
#define PITCH 136   // f16 units per LDS code row (128 + 8 pad)
#define TAU  0.5f

typedef _Float16 half8 __attribute__((ext_vector_type(8)));
typedef float   f32x4 __attribute__((ext_vector_type(4)));

__device__ __forceinline__ double sq8(float4 x0, float4 x1, float4 a0, float4 a1) {
  double s = (double)(x0.x - a0.x) * (x0.x - a0.x);
  s += (double)(x0.y - a0.y) * (x0.y - a0.y);
  s += (double)(x0.z - a0.z) * (x0.z - a0.z);
  s += (double)(x0.w - a0.w) * (x0.w - a0.w);
  s += (double)(x1.x - a1.x) * (x1.x - a1.x);
  s += (double)(x1.y - a1.y) * (x1.y - a1.y);
  s += (double)(x1.z - a1.z) * (x1.z - a1.z);
  s += (double)(x1.w - a1.w) * (x1.w - a1.w);
  return s;
}

__global__ __launch_bounds__(512, 6)
void pvq_main(const float* __restrict__ inp, const float* __restrict__ emb,
              float* __restrict__ outq, int* __restrict__ idx_ws,
              float* __restrict__ dist_ws) {
  __shared__ _Float16 elds[KC * PITCH];  // 34 KB
  __shared__ float    e2s[KC];

  const int c    = blockIdx.y;
  const int t    = threadIdx.x;
  const int lane = t & 63;
  const int wid  = t >> 6;
  const int nf   = lane & 15;   // code index within 16-tile / A row index
  const int quad = lane >> 4;

  const float* ebase = emb + (size_t)c * KC * DS;

  // ---- stage e -> f16 LDS (coalesced float4), e2 fused via 32-lane tree ----
  {
    const float4* eg = (const float4*)ebase;
    #pragma unroll
    for (int it = 0; it < 8; ++it) {
      int i = it * 512 + t;            // 0..4095
      float4 v = eg[i];
      int code = i >> 5;               // 32 float4 per code row
      int dpos = (i & 31) << 2;
      _Float16* p = &elds[code * PITCH + dpos];
      p[0] = (_Float16)v.x; p[1] = (_Float16)v.y;
      p[2] = (_Float16)v.z; p[3] = (_Float16)v.w;
      float s = fmaf(v.x, v.x, fmaf(v.y, v.y, fmaf(v.z, v.z, v.w * v.w)));
      #pragma unroll
      for (int off = 1; off < 32; off <<= 1) s += __shfl_xor(s, off);
      if ((t & 31) == 0) e2s[code] = 0.5f * s;
    }
  }
  __syncthreads();

  // ---- 2 row-tiles (16 rows each) per wave; block covers 256 rows ----
  const int rowblk = blockIdx.x * 256 + wid * 32;
  #pragma unroll 1
  for (int tile = 0; tile < 2; ++tile) {
    const int n0 = rowblk + tile * 16;
    const float* xrow = inp + (size_t)(n0 + nf) * DF + c * DS;

    // A-frags as NAMED registers (row = nf, depth chunk = quad*8 + j + 32*kc)
    half8 af0, af1, af2, af3;
    float x2 = 0.f;
#define LOADA(AF, KC4) { \
      const float4* xp = (const float4*)(xrow + (KC4) * 32 + quad * 8); \
      float4 v0 = xp[0], v1 = xp[1]; \
      x2 = fmaf(v0.x, v0.x, x2); x2 = fmaf(v0.y, v0.y, x2); \
      x2 = fmaf(v0.z, v0.z, x2); x2 = fmaf(v0.w, v0.w, x2); \
      x2 = fmaf(v1.x, v1.x, x2); x2 = fmaf(v1.y, v1.y, x2); \
      x2 = fmaf(v1.z, v1.z, x2); x2 = fmaf(v1.w, v1.w, x2); \
      AF[0] = (_Float16)v0.x; AF[1] = (_Float16)v0.y; \
      AF[2] = (_Float16)v0.z; AF[3] = (_Float16)v0.w; \
      AF[4] = (_Float16)v1.x; AF[5] = (_Float16)v1.y; \
      AF[6] = (_Float16)v1.z; AF[7] = (_Float16)v1.w; }
    LOADA(af0, 0) LOADA(af1, 1) LOADA(af2, 2) LOADA(af3, 3)
#undef LOADA
    // full |x_row|^2 to every lane holding that row (reduce across quads)
    x2 += __shfl_xor(x2, 16);
    x2 += __shfl_xor(x2, 32);

    // ---- fused MFMA + top-2, all state in NAMED scalars ----
    float S10 = 1e30f, S11 = 1e30f, S12 = 1e30f, S13 = 1e30f;
    float S20 = 1e30f, S21 = 1e30f, S22 = 1e30f, S23 = 1e30f;
    int   K10 = 0, K11 = 0, K12 = 0, K13 = 0;
    int   K20 = 0, K21 = 0, K22 = 0, K23 = 0;
#define TOP2(S1, S2, K1, K2, SV, KI) { \
      float _s = (SV); \
      if (_s < S1)      { S2 = S1; K2 = K1; S1 = _s; K1 = (KI); } \
      else if (_s < S2) { S2 = _s; K2 = (KI); } }

    #pragma unroll
    for (int nt = 0; nt < 8; ++nt) {
      const int krow = (nt * 16 + nf) * PITCH;
      f32x4 acc = (f32x4){0.f, 0.f, 0.f, 0.f};
      half8 b0 = *(const half8*)&elds[krow +  0 + quad * 8];
      half8 b1 = *(const half8*)&elds[krow + 32 + quad * 8];
      half8 b2 = *(const half8*)&elds[krow + 64 + quad * 8];
      half8 b3 = *(const half8*)&elds[krow + 96 + quad * 8];
      acc = __builtin_amdgcn_mfma_f32_16x16x32_f16(af0, b0, acc, 0, 0, 0);
      acc = __builtin_amdgcn_mfma_f32_16x16x32_f16(af1, b1, acc, 0, 0, 0);
      acc = __builtin_amdgcn_mfma_f32_16x16x32_f16(af2, b2, acc, 0, 0, 0);
      acc = __builtin_amdgcn_mfma_f32_16x16x32_f16(af3, b3, acc, 0, 0, 0);
      const float e2v = e2s[nt * 16 + nf];
      const int   ki  = nt * 16 + nf;
      TOP2(S10, S20, K10, K20, e2v - acc[0], ki)
      TOP2(S11, S21, K11, K21, e2v - acc[1], ki)
      TOP2(S12, S22, K12, K22, e2v - acc[2], ki)
      TOP2(S13, S23, K13, K23, e2v - acc[3], ki)
    }
#undef TOP2

    // ---- merge across the 16 lanes of each quad-group (serialized off-loop) ----
#define MERGE1(S1, K1, S2, K2) { \
      float o1 = __shfl_xor(S1, off); int ok1 = __shfl_xor(K1, off); \
      float o2 = __shfl_xor(S2, off); int ok2 = __shfl_xor(K2, off); \
      bool to = (o1 < S1) || (o1 == S1 && ok1 < K1); \
      float w1 = to ? o1 : S1; int wk1 = to ? ok1 : K1; \
      float l1 = to ? S1 : o1; int lk1 = to ? K1 : ok1; \
      float n2 = l1; int nk2 = lk1; \
      if (S2 < n2) { n2 = S2; nk2 = K2; } \
      if (o2 < n2) { n2 = o2; nk2 = ok2; } \
      S1 = w1; K1 = wk1; S2 = n2; K2 = nk2; }
    #pragma unroll 1
    for (int off = 1; off < 16; off <<= 1) {
      MERGE1(S10, K10, S20, K20)
      MERGE1(S11, K11, S21, K21)
      MERGE1(S12, K12, S22, K22)
      MERGE1(S13, K13, S23, K23)
    }
#undef MERGE1

    // ---- winners: quad-group g owns rows n0 + 4g + r (values quad-uniform) ----
    int kb0, kb1, kb2r, kb3; float p0, p1, p2, p3;
#define WINNER(RR, S1, K1, S2, K2, KBOUT, POUT) { \
      const int row = quad * 4 + (RR); \
      const float x2r = __shfl(x2, row); \
      int _kb = K1; float _p; \
      if (S2 - S1 < TAU) { \
        int _kb2 = K2; \
        const float4* xp = (const float4*)(inp + (size_t)(n0 + row) * DF + c * DS); \
        const float4* eA = (const float4*)(ebase + (size_t)_kb  * DS); \
        const float4* eB = (const float4*)(ebase + (size_t)_kb2 * DS); \
        float4 x0 = xp[nf], x1v = xp[16 + nf]; \
        float4 a0 = eA[nf], a1 = eA[16 + nf]; \
        float4 b0 = eB[nf], b1 = eB[16 + nf]; \
        double pA = sq8(x0, x1v, a0, a1); \
        double pB = sq8(x0, x1v, b0, b1); \
        for (int off = 1; off < 16; off <<= 1) { \
          pA += __shfl_xor(pA, off); \
          pB += __shfl_xor(pB, off); \
        } \
        if (pB < pA || (pB == pA && _kb2 < _kb)) { _kb = _kb2; _p = (float)pB; } \
        else                                     { _p = (float)pA; } \
      } else { _p = x2r + 2.f * S1; } \
      KBOUT = _kb; POUT = _p; }
    WINNER(0, S10, K10, S20, K20, kb0, p0)
    WINNER(1, S11, K11, S21, K21, kb1, p1)
    WINNER(2, S12, K12, S22, K22, kb2r, p2)
    WINNER(3, S13, K13, S23, K23, kb3, p3)
#undef WINNER

    // ---- gather fp32 code rows + store; contiguous 256 B per quad per instr ----
    {
      const float4* e0 = (const float4*)(ebase + (size_t)kb0 * DS);
      const float4* e1 = (const float4*)(ebase + (size_t)kb1 * DS);
      float4 q0a = e0[nf], q0b = e0[16 + nf];
      float4 q1a = e1[nf], q1b = e1[16 + nf];
      float4* o0 = (float4*)(outq + (size_t)(n0 + quad * 4 + 0) * DF + c * DS);
      float4* o1 = (float4*)(outq + (size_t)(n0 + quad * 4 + 1) * DF + c * DS);
      o0[nf] = q0a; o0[16 + nf] = q0b;
      o1[nf] = q1a; o1[16 + nf] = q1b;
    }
    {
      const float4* e2p = (const float4*)(ebase + (size_t)kb2r * DS);
      const float4* e3p = (const float4*)(ebase + (size_t)kb3  * DS);
      float4 q2a = e2p[nf], q2b = e2p[16 + nf];
      float4 q3a = e3p[nf], q3b = e3p[16 + nf];
      float4* o2 = (float4*)(outq + (size_t)(n0 + quad * 4 + 2) * DF + c * DS);
      float4* o3 = (float4*)(outq + (size_t)(n0 + quad * 4 + 3) * DF + c * DS);
      o2[nf] = q2a; o2[16 + nf] = q2b;
      o3[nf] = q3a; o3[16 + nf] = q3b;
    }
    // planar [c][n] workspace: wave's 32 tokens = one 128 B line per array
    if (nf == 0) {
      const int nb = n0 + quad * 4;
      idx_ws[(size_t)c * NTOK + nb + 0]  = kb0;
      idx_ws[(size_t)c * NTOK + nb + 1]  = kb1;
      idx_ws[(size_t)c * NTOK + nb + 2]  = kb2r;
      idx_ws[(size_t)c * NTOK + nb + 3]  = kb3;
      dist_ws[(size_t)c * NTOK + nb + 0] = p0;
      dist_ws[(size_t)c * NTOK + nb + 1] = p1;
      dist_ws[(size_t)c * NTOK + nb + 2] = p2;
      dist_ws[(size_t)c * NTOK + nb + 3] = p3;
    }
  }
}

__global__ void pvq_tail(const int* __restrict__ idx_ws,
                         const float* __restrict__ dist_ws,
                         float* __restrict__ out_enc,
                         float* __restrict__ out_loss) {
  int n = blockIdx.x * blockDim.x + threadIdx.x;
  if (n >= NTOK) return;
  int   kx = idx_ws[n];
  int   ky = idx_ws[NTOK + n];
  int   kz = idx_ws[2 * NTOK + n];
  int   kw = idx_ws[3 * NTOK + n];
  float dx = dist_ws[n];
  float dy = dist_ws[NTOK + n];
  float dz = dist_ws[2 * NTOK + n];
  float dw = dist_ws[3 * NTOK + n];
  int enc = ((kx * KC + ky) * KC + kz) * KC + kw;
  out_enc[n]  = (float)enc;
  out_loss[n] = 1.25f * (((dx + dy) + dz) + dw);
}

extern "C" void kernel_launch(void* const* d_in, const int* in_sizes, int n_in,
                              void* d_out, int out_size, void* d_ws, size_t ws_size,
                              hipStream_t stream) {
  const float* inp = (const float*)d_in[0];
  const float* emb = (const float*)d_in[1];

  float* outq     = (float*)d_out;
  float* out_enc  = outq + (size_t)NTOK * DF;
  float* out_loss = out_enc + NTOK;

  int*   idx_ws  = (int*)d_ws;
  float* dist_ws = (float*)d_ws + (size_t)NTOK * CS;

  dim3 grid(NTOK / 256, CS);   // 512 x 4
  pvq_main<<<grid, 512, 0, stream>>>(inp, emb, outq, idx_ws, dist_ws);
  pvq_tail<<<(NTOK + 255) / 256, 256, 0, stream>>>(idx_ws, dist_ws, out_enc, out_loss);
}